// Round 13
// baseline (48.711 us; speedup 1.0000x reference)
//
#include <hip/hip_runtime.h>
#include <hip/hip_bf16.h>

// BasicBlock (ReActNet) fused pipeline, MI355X gfx950.  R13 = R12 +
// (1) (2m,2n) wave split: wave = 2 m-frags x 2 och-frags -> A LDS redundancy
//     8x -> 4x (DS 768->384 cyc/phase); B via L2 (32KB/phase) overlaps on the
//     VMEM pipe. MFMA/SIMD unchanged (MX-scaled fp8 32x32x64, scales=1.0).
// (2) x residual prefetched to LDS ([och][96px] f32, 98KB) during conv3x3 via
//     drip-fed global_load_lds -- un-serializes epilogue-1's 25.7MB HBM read.

typedef unsigned short u16;
typedef unsigned char  u8;
typedef unsigned int   u32;
typedef unsigned long long u64;
typedef float f32x4 __attribute__((ext_vector_type(4)));
typedef long  long2v __attribute__((ext_vector_type(2)));
typedef int   v8i  __attribute__((ext_vector_type(8)));
typedef float v16f __attribute__((ext_vector_type(16)));

#define GLD16(gsrc, ldst) \
  __builtin_amdgcn_global_load_lds((__attribute__((address_space(1))) void*)(gsrc), \
                                   (__attribute__((address_space(3))) void*)(ldst), 16, 0, 0)

__device__ __forceinline__ float b2f(u16 u) {
  union { unsigned int i; float f; } c; c.i = ((unsigned int)u) << 16; return c.f;
}
__device__ __forceinline__ u16 f2b(float f) {
  unsigned int u = __builtin_bit_cast(unsigned int, f);
  unsigned int r = (u + 0x7FFFu + ((u >> 16) & 1u)) >> 16;   // RNE
  return (u16)r;
}
__device__ __forceinline__ u8 f2sign8(float v) {   // fp8 e4m3 of sign(v)
  return (v > 0.f) ? 0x38 : ((v < 0.f) ? 0xB8 : 0x00);
}
__device__ __forceinline__ v8i mkv8(long2v a, long2v b) {
  union { long2v l[2]; v8i v; } u; u.l[0] = a; u.l[1] = b; return u.v;
}

// ---- prep(blk<512) + act1(blk>=512) merged (identical to R12) ----
__global__ __launch_bounds__(256) void prep_act_kernel(
    const float* __restrict__ w1, const float* __restrict__ w2,
    const float* __restrict__ g1, const float* __restrict__ be1,
    const float* __restrict__ m1, const float* __restrict__ v1,
    const float* __restrict__ g2, const float* __restrict__ be2,
    const float* __restrict__ m2, const float* __restrict__ v2,
    u8* __restrict__ w1T, u8* __restrict__ w2T,
    float* __restrict__ ab,
    float* __restrict__ lossdst, const float* __restrict__ lossin,
    const float* __restrict__ x, const float* __restrict__ b11,
    u8* __restrict__ act1pad)
{
  __shared__ float wrow[2304];
  __shared__ float red[256];
  __shared__ u8 lds8[112 * 64];
  const int t = threadIdx.x;
  const int blk = blockIdx.x;

  if (blk < 512) {   // ================= prep =================
    float s = 0.f;
    if (blk < 256) {
      const int o = blk;
      const float4* src = (const float4*)(w1 + o * 2304);
#pragma unroll
      for (int i = 0; i < 3; ++i) {
        int c = i * 256 + t;
        if (c < 576) {
          float4 v = src[c];
          wrow[c * 4 + 0] = v.x; wrow[c * 4 + 1] = v.y;
          wrow[c * 4 + 2] = v.z; wrow[c * 4 + 3] = v.w;
          s += fabsf(v.x) + fabsf(v.y) + fabsf(v.z) + fabsf(v.w);
        }
      }
    } else {
      const int o = blk - 256;
      float v = w2[o * 256 + t];
      wrow[t] = v;
      s = fabsf(v);
    }
    red[t] = s;
    __syncthreads();
    for (int st = 128; st > 0; st >>= 1) { if (t < st) red[t] += red[t + st]; __syncthreads(); }
    if (blk < 256) {
      const int o = blk;
      for (int it = t; it < 288; it += 256) {   // (tap, ci-octet)
        int tap = it >> 5, ci8 = it & 31;
        u64 pack = 0;
#pragma unroll
        for (int k = 0; k < 8; ++k)
          pack |= ((u64)f2sign8(wrow[(ci8 * 8 + k) * 9 + tap])) << (8 * k);
        int c64 = ci8 >> 3, kh = (ci8 >> 2) & 1, slot = ci8 & 3;
        *(u64*)(w1T + (size_t)((tap * 4 + c64) * 2 + kh) * 8192 + o * 32 + slot * 8) = pack;
      }
      if (t == 0) {
        float scale = red[0] / 2304.f;
        float inv = g1[o] / sqrtf(v1[o] + 1e-5f);
        ab[o]       = scale * inv;
        ab[256 + o] = be1[o] - m1[o] * inv;
      }
    } else {
      const int o = blk - 256;
      if (t < 32) {
        u64 pack = 0;
#pragma unroll
        for (int k = 0; k < 8; ++k)
          pack |= ((u64)f2sign8(wrow[t * 8 + k])) << (8 * k);
        int c64 = t >> 3, kh = (t >> 2) & 1, slot = t & 3;
        *(u64*)(w2T + (size_t)(c64 * 2 + kh) * 8192 + o * 32 + slot * 8) = pack;
      }
      if (t == 0) {
        float scale = red[0] / 256.f;
        float inv = g2[o] / sqrtf(v2[o] + 1e-5f);
        ab[512 + o] = scale * inv;
        ab[768 + o] = be2[o] - m2[o] * inv;
      }
    }
    if (blk == 0 && t == 0) lossdst[0] = lossin[0];
    return;
  }

  // ================= act1 (linear ci layout) =================
  const int b2i = blk - 512;             // 0..895
  const int pxgrp = b2i % 7;
  const int cgrp  = (b2i / 7) & 3;
  const int img   = b2i / 28;
  const int c0 = cgrp * 64;
  const int p0 = pxgrp * 112;
  const float* xb = x + (size_t)img * 200704;
#pragma unroll
  for (int it = 0; it < 7; ++it) {
    int flat = it * 256 + t;           // c:64 x p4:28
    int c = flat / 28;
    int p = (flat % 28) * 4;
    float4 v4 = *(const float4*)(xb + (size_t)(c0 + c) * 784 + p0 + p);
    float bb = b11[c0 + c];
    lds8[(p + 0) * 64 + c] = f2sign8(v4.x + bb);
    lds8[(p + 1) * 64 + c] = f2sign8(v4.y + bb);
    lds8[(p + 2) * 64 + c] = f2sign8(v4.z + bb);
    lds8[(p + 3) * 64 + c] = f2sign8(v4.w + bb);
  }
  __syncthreads();
#pragma unroll
  for (int it = 0; it < 7; ++it) {
    int flat = it * 256 + t;           // px:112 x c4:16
    int px = flat >> 4;
    int c4 = (flat & 15) * 4;
    u32 v = *(const u32*)(lds8 + px * 64 + c4);
    int pr = (px * 293) >> 13;         // px/28
    int pc = px - 28 * pr;
    size_t dst = ((size_t)img * 900 + (size_t)(pxgrp * 4 + 1 + pr) * 30 + 1 + pc) * 256 + c0 + c4;
    *(u32*)(act1pad + dst) = v;
  }
  if (pxgrp == 0 && cgrp == 0) {
    for (int idx = t; idx < 116 * 64; idx += 256) {
      int bp = idx >> 6;
      int l4 = (idx & 63) * 4;
      int br, bc;
      if (bp < 30)      { br = 0;       bc = bp; }
      else if (bp < 60) { br = 29;      bc = bp - 30; }
      else if (bp < 88) { br = bp - 59; bc = 0; }
      else              { br = bp - 87; bc = 29; }
      *(u32*)(act1pad + ((size_t)img * 900 + br * 30 + bc) * 256 + l4) = 0u;
    }
  }
}

// ---------------- fused conv3x3 + conv1x1, MX fp8, (2m,2n) wave split ----------------
__global__ __launch_bounds__(512, 1) void fused_kernel(
    const u8* __restrict__ act1pad, const float* __restrict__ x,
    const u8* __restrict__ w1T, const u8* __restrict__ w2T,
    const float* __restrict__ ab,
    const float* __restrict__ b12, const float* __restrict__ a1,
    const float* __restrict__ b13, const float* __restrict__ b21,
    const float* __restrict__ b22, const float* __restrict__ a2,
    const float* __restrict__ b23,
    float* __restrict__ dout)
{
  __shared__ __align__(16) u8 win[51200];    // 180px window (+OOB slack); reused for act2
  __shared__ __align__(16) u8 xbuf[98304];   // x residual [och 256][96 px] f32

  const int t = threadIdx.x;
  const int w = t >> 6;
  const int l = t & 63;
  const int l31 = l & 31;
  const int h32 = l >> 5;              // k-half selector
  const int mg = w & 1;                // m-pair group (m = mg*2 + mi)
  const int ng = w >> 1;               // och quad (64 och)
  const int pxblk = blockIdx.x;        // 224
  const int img = pxblk / 7;
  const int rowgrp = pxblk % 7;

  // per-lane epilogue params for nf = 0,1 (och = ng*64 + nf*32 + l31)
  float al1[2], bt1[2], pA1[2], pS1[2], pB1[2], p21[2];
  float al2[2], bt2[2], pA2[2], pS2[2], pB2[2];
  int Ov[2];
#pragma unroll
  for (int nf = 0; nf < 2; ++nf) {
    int O = ng * 64 + nf * 32 + l31;
    Ov[nf] = O;
    al1[nf] = ab[O];       bt1[nf] = ab[256 + O];
    al2[nf] = ab[512 + O]; bt2[nf] = ab[768 + O];
    pA1[nf] = b12[O]; pS1[nf] = a1[O]; pB1[nf] = b13[O]; p21[nf] = b21[O];
    pA2[nf] = b22[O]; pS2[nf] = a2[O]; pB2[nf] = b23[O];
  }

  int basepix[2];
#pragma unroll
  for (int mi = 0; mi < 2; ++mi) {
    int pm = (mg * 2 + mi) * 32 + l31;
    int r = (pm * 293) >> 13;          // pm/28
    basepix[mi] = r * 30 + (pm - 28 * r);
  }

  char* wl = (char*)win;
  char* xl = (char*)xbuf;

  v16f acc[2][2];
  v16f zero16 = {0.f,0.f,0.f,0.f,0.f,0.f,0.f,0.f,0.f,0.f,0.f,0.f,0.f,0.f,0.f,0.f};
#pragma unroll
  for (int mi = 0; mi < 2; ++mi)
#pragma unroll
    for (int nf = 0; nf < 2; ++nf) acc[mi][nf] = zero16;

  // ---- prologue: stage window (180px x 256B), XOR pre-swizzled source ----
  const u8* winsrc = act1pad + ((size_t)img * 900 + (size_t)rowgrp * 120) * 256;
#pragma unroll
  for (int i = 0; i < 5; ++i) {
    int c = i * 512 + t;
    int pix = c >> 4, j = c & 15;
    GLD16((const char*)winsrc + pix * 256 + ((j ^ (pix & 15)) << 4), wl + c * 16);
  }
  if (t < 320) {
    int c = 2560 + t;
    int pix = c >> 4, j = c & 15;
    GLD16((const char*)winsrc + pix * 256 + ((j ^ (pix & 15)) << 4), wl + c * 16);
  }
  asm volatile("s_waitcnt vmcnt(0)" ::: "memory");
  __builtin_amdgcn_s_barrier();

  // ---- loaders / compute ----
  auto LOADB3 = [&](long2v (*dst)[2], int s) {   // 2 n-frags x 32B/lane
    int sc = (s < 36) ? s : 0;
    const char* base = (const char*)w1T + (size_t)sc * 16384 + h32 * 8192;
#pragma unroll
    for (int nf = 0; nf < 2; ++nf) {
      const char* p = base + (ng * 64 + nf * 32 + l31) * 32;
      dst[nf][0] = *(const long2v*)(p);
      dst[nf][1] = *(const long2v*)(p + 16);
    }
  };
  auto DSA3 = [&](long2v (*dst)[2], int s) {     // 2 m-frags x 32B/lane
    int sc = (s < 36) ? s : 0;
    int tap = sc >> 2;
    int c64 = sc & 3;
    int ti = (tap * 11) >> 5;                    // tap/3
    int tapoff = ti * 30 + (tap - 3 * ti);
    int off = c64 * 64 + h32 * 32;
#pragma unroll
    for (int mi = 0; mi < 2; ++mi) {
      int wp = basepix[mi] + tapoff;
      int sw = (wp & 15) << 4;
      const char* p = wl + wp * 256;
      dst[mi][0] = *(const long2v*)(p + ((off)      ^ sw));
      dst[mi][1] = *(const long2v*)(p + ((off + 16) ^ sw));
    }
  };
  auto COMP = [&](long2v (*a)[2], long2v (*bv)[2]) {   // 4 MFMA
    __builtin_amdgcn_s_setprio(1);
#pragma unroll
    for (int mi = 0; mi < 2; ++mi) {
      v8i a8 = mkv8(a[mi][0], a[mi][1]);
#pragma unroll
      for (int nf = 0; nf < 2; ++nf)
        acc[mi][nf] = __builtin_amdgcn_mfma_scale_f32_32x32x64_f8f6f4(
            a8, mkv8(bv[nf][0], bv[nf][1]), acc[mi][nf],
            0, 0, 0, 0x7F7F7F7Fu, 0, 0x7F7F7F7Fu);
    }
    __builtin_amdgcn_s_setprio(0);
  };
  auto XSTAGE = [&](int c) {           // stage 8KB chunk c of x [och][96px] f32
    int u = c * 512 + t;               // 16B unit; och = u/24, rem = u%24
    int och = ((u >> 3) * 21846) >> 16;
    int rem = u - och * 24;
    const float* src = x + ((size_t)(img * 256 + och)) * 784 + rowgrp * 112 + rem * 4;
    GLD16(src, xl + u * 16);
  };

  // ---- conv3x3: 36 phases, A dbuf + B 3-set rotation + x drip-stage ----
  long2v A0[2][2], A1[2][2];
  long2v b0[2][2], b1[2][2], b2[2][2];
  DSA3(A0, 0); LOADB3(b0, 0); LOADB3(b1, 1);
#pragma unroll 1
  for (int i = 0; i < 6; ++i) {
    int p = i * 6;
    LOADB3(b2, p + 2); DSA3(A1, p + 1); COMP(A0, b0);
    XSTAGE(i * 2);
    LOADB3(b0, p + 3); DSA3(A0, p + 2); COMP(A1, b1);
    LOADB3(b1, p + 4); DSA3(A1, p + 3); COMP(A0, b2);
    LOADB3(b2, p + 5); DSA3(A0, p + 4); COMP(A1, b0);
    XSTAGE(i * 2 + 1);
    LOADB3(b0, p + 6); DSA3(A1, p + 5); COMP(A0, b1);
    LOADB3(b1, p + 7); DSA3(A0, p + 6); COMP(A1, b2);
  }
  __syncthreads();   // drains vmcnt (x chunks landed) + all window reads done

  // ---- epilogue 1: out1 = BN(conv)+x -> bias/PReLU/bias; act2 -> LDS ----
  // C/D row = (reg&3) + 8*rp + 4*h32; pixel = m*32 + that; och = Ov[nf].
  u32 pk[2][2][4][2];
#pragma unroll
  for (int mi = 0; mi < 2; ++mi) {
    int m = mg * 2 + mi;
#pragma unroll
    for (int rp = 0; rp < 4; ++rp) {
      int pixbase = m * 32 + 8 * rp + 4 * h32;
      bool valid = (m < 3) || (rp < 2);
#pragma unroll
      for (int nf = 0; nf < 2; ++nf) {
        int O = Ov[nf];
        float xv[4] = {0.f, 0.f, 0.f, 0.f};
        if (m < 3) {                   // x from LDS ([och][96px] f32)
          f32x4 xr = *(const f32x4*)(xl + O * 384 + pixbase * 4);
          xv[0] = xr[0]; xv[1] = xr[1]; xv[2] = xr[2]; xv[3] = xr[3];
        } else if (valid) {            // m==3, rp<2: direct global
          int hwm = rowgrp * 112 + pixbase;
          float4 xr = *(const float4*)(x + ((size_t)(img * 256 + O) * 784 + hwm));
          xv[0] = xr.x; xv[1] = xr.y; xv[2] = xr.z; xv[3] = xr.w;
        }
        float o1v[4];
#pragma unroll
        for (int reg = 0; reg < 4; ++reg) {
          int pix = pixbase + reg;
          float v = acc[mi][nf][rp * 4 + reg] * al1[nf] + bt1[nf] + xv[reg];
          float t1 = v + pA1[nf];
          t1 = (t1 > 0.f) ? t1 : pS1[nf] * t1;
          o1v[reg] = t1 + pB1[nf];
          wl[pix * 256 + (O ^ ((pix & 15) << 4))] = f2sign8(o1v[reg] + p21[nf]);
        }
        pk[mi][nf][rp][0] = (u32)f2b(o1v[0]) | ((u32)f2b(o1v[1]) << 16);
        pk[mi][nf][rp][1] = (u32)f2b(o1v[2]) | ((u32)f2b(o1v[3]) << 16);
      }
    }
  }
#pragma unroll
  for (int mi = 0; mi < 2; ++mi)
#pragma unroll
    for (int nf = 0; nf < 2; ++nf) acc[mi][nf] = zero16;

  asm volatile("s_waitcnt lgkmcnt(0)" ::: "memory");   // act2 LDS stores complete
  __builtin_amdgcn_s_barrier();

  // ---- conv1x1: 4 phases (K=256), A dbuf + B 2-set rotation ----
  auto LOADB1 = [&](long2v (*dst)[2], int sp) {
    const char* base = (const char*)w2T + (size_t)sp * 16384 + h32 * 8192;
#pragma unroll
    for (int nf = 0; nf < 2; ++nf) {
      const char* p = base + (ng * 64 + nf * 32 + l31) * 32;
      dst[nf][0] = *(const long2v*)(p);
      dst[nf][1] = *(const long2v*)(p + 16);
    }
  };
  auto DSA1 = [&](long2v (*dst)[2], int sp) {
    int off = sp * 64 + h32 * 32;
#pragma unroll
    for (int mi = 0; mi < 2; ++mi) {
      int pm = (mg * 2 + mi) * 32 + l31;
      int sw = (pm & 15) << 4;
      const char* p = wl + pm * 256;
      dst[mi][0] = *(const long2v*)(p + ((off)      ^ sw));
      dst[mi][1] = *(const long2v*)(p + ((off + 16) ^ sw));
    }
  };
  DSA1(A0, 0); LOADB1(b0, 0);
  DSA1(A1, 1); LOADB1(b1, 1); COMP(A0, b0);
  DSA1(A0, 2); LOADB1(b0, 2); COMP(A1, b1);
  DSA1(A1, 3); LOADB1(b1, 3); COMP(A0, b0);
  COMP(A1, b1);

  // ---- epilogue 2: out2 -> dout NCHW f32 ----
#pragma unroll
  for (int mi = 0; mi < 2; ++mi) {
    int m = mg * 2 + mi;
#pragma unroll
    for (int rp = 0; rp < 4; ++rp) {
      bool valid = (m < 3) || (rp < 2);
      if (!valid) continue;
      int pixbase = m * 32 + 8 * rp + 4 * h32;
      int hwm = rowgrp * 112 + pixbase;
#pragma unroll
      for (int nf = 0; nf < 2; ++nf) {
        int O = Ov[nf];
        float res[4];
        res[0] = b2f((u16)(pk[mi][nf][rp][0] & 0xFFFF));
        res[1] = b2f((u16)(pk[mi][nf][rp][0] >> 16));
        res[2] = b2f((u16)(pk[mi][nf][rp][1] & 0xFFFF));
        res[3] = b2f((u16)(pk[mi][nf][rp][1] >> 16));
        float r4v[4];
#pragma unroll
        for (int reg = 0; reg < 4; ++reg) {
          float v = acc[mi][nf][rp * 4 + reg] * al2[nf] + bt2[nf] + res[reg];
          float t1 = v + pA2[nf];
          t1 = (t1 > 0.f) ? t1 : pS2[nf] * t1;
          r4v[reg] = t1 + pB2[nf];
        }
        float4 r4 = {r4v[0], r4v[1], r4v[2], r4v[3]};
        *(float4*)(dout + ((size_t)(img * 256 + O)) * 784 + hwm) = r4;
      }
    }
  }
}

// ---------------- launcher ----------------
extern "C" void kernel_launch(void* const* d_in, const int* in_sizes, int n_in,
                              void* d_out, int out_size, void* d_ws, size_t ws_size,
                              hipStream_t stream) {
  const float* x    = (const float*)d_in[0];
  const float* loss = (const float*)d_in[1];
  const float* b11  = (const float*)d_in[2];
  const float* b12  = (const float*)d_in[3];
  const float* b13  = (const float*)d_in[4];
  const float* b21  = (const float*)d_in[5];
  const float* b22  = (const float*)d_in[6];
  const float* b23  = (const float*)d_in[7];
  const float* w1   = (const float*)d_in[8];
  const float* w2   = (const float*)d_in[9];
  const float* g1   = (const float*)d_in[10];
  const float* be1  = (const float*)d_in[11];
  const float* m1   = (const float*)d_in[12];
  const float* v1   = (const float*)d_in[13];
  const float* g2   = (const float*)d_in[14];
  const float* be2  = (const float*)d_in[15];
  const float* m2   = (const float*)d_in[16];
  const float* v2   = (const float*)d_in[17];
  const float* a1   = (const float*)d_in[18];
  const float* a2   = (const float*)d_in[19];

  char* ws = (char*)d_ws;
  u8*    act1pad = (u8*)(ws + 0ull);           // fp8 (32,30,30,256) = 7,372,800
  u8*    w1T     = (u8*)(ws + 7372800ull);     // 36 x 16KB = 589,824
  u8*    w2T     = (u8*)(ws + 7962624ull);     // 4 x 16KB = 65,536
  float* ab      = (float*)(ws + 8028160ull);  // 4 x 256 f32

  float* out = (float*)d_out;

  prep_act_kernel<<<1408, 256, 0, stream>>>(w1, w2, g1, be1, m1, v1, g2, be2, m2, v2,
                                            w1T, w2T, ab, out + (out_size - 1), loss,
                                            x, b11, act1pad);
  fused_kernel<<<224, 512, 0, stream>>>(act1pad, x, w1T, w2T, ab,
                                        b12, a1, b13, b21, b22, a2, b23, out);
}

// Round 15
// 43.644 us; speedup vs baseline: 1.1161x; 1.1161x over previous
//
#include <hip/hip_runtime.h>
#include <hip/hip_bf16.h>

// BasicBlock (ReActNet) fused pipeline, MI355X gfx950.  R15 = R14 with the
// compile fix (window-clear uses an explicit f32x4 zero, not zero16.lo).
// act1 folded INTO the fused kernel's prologue (per-block window computed
// directly from x via LDS transpose) -- eliminates the act1pad HBM round-trip,
// the big prep_act kernel, its launch gap, and the GLD16 window stage.
// Main loop: (2m,2n) wave split, MX-scaled fp8 32x32x64 (scales=1.0, exact).

typedef unsigned short u16;
typedef unsigned char  u8;
typedef unsigned int   u32;
typedef unsigned long long u64;
typedef float f32x4 __attribute__((ext_vector_type(4)));
typedef long  long2v __attribute__((ext_vector_type(2)));
typedef int   v8i  __attribute__((ext_vector_type(8)));
typedef float v16f __attribute__((ext_vector_type(16)));

__device__ __forceinline__ float b2f(u16 u) {
  union { unsigned int i; float f; } c; c.i = ((unsigned int)u) << 16; return c.f;
}
__device__ __forceinline__ u16 f2b(float f) {
  unsigned int u = __builtin_bit_cast(unsigned int, f);
  unsigned int r = (u + 0x7FFFu + ((u >> 16) & 1u)) >> 16;   // RNE
  return (u16)r;
}
__device__ __forceinline__ u8 f2sign8(float v) {   // fp8 e4m3 of sign(v)
  return (v > 0.f) ? 0x38 : ((v < 0.f) ? 0xB8 : 0x00);
}
__device__ __forceinline__ v8i mkv8(long2v a, long2v b) {
  union { long2v l[2]; v8i v; } u; u.l[0] = a; u.l[1] = b; return u.v;
}

// ---- prep: fp8 sign weights [phase][och][32B] (w1T/w2T), BN fold, loss ----
__global__ __launch_bounds__(256) void prep_kernel(
    const float* __restrict__ w1, const float* __restrict__ w2,
    const float* __restrict__ g1, const float* __restrict__ be1,
    const float* __restrict__ m1, const float* __restrict__ v1,
    const float* __restrict__ g2, const float* __restrict__ be2,
    const float* __restrict__ m2, const float* __restrict__ v2,
    u8* __restrict__ w1T, u8* __restrict__ w2T,
    float* __restrict__ ab,
    float* __restrict__ lossdst, const float* __restrict__ lossin)
{
  __shared__ float wrow[2304];
  __shared__ float red[256];
  const int t = threadIdx.x;
  const int blk = blockIdx.x;
  float s = 0.f;
  if (blk < 256) {                       // w1 row o: stage coalesced, then pack
    const int o = blk;
    const float4* src = (const float4*)(w1 + o * 2304);
#pragma unroll
    for (int i = 0; i < 3; ++i) {
      int c = i * 256 + t;
      if (c < 576) {
        float4 v = src[c];
        wrow[c * 4 + 0] = v.x; wrow[c * 4 + 1] = v.y;
        wrow[c * 4 + 2] = v.z; wrow[c * 4 + 3] = v.w;
        s += fabsf(v.x) + fabsf(v.y) + fabsf(v.z) + fabsf(v.w);
      }
    }
  } else {
    const int o = blk - 256;
    float v = w2[o * 256 + t];
    wrow[t] = v;
    s = fabsf(v);
  }
  red[t] = s;
  __syncthreads();
  for (int st = 128; st > 0; st >>= 1) { if (t < st) red[t] += red[t + st]; __syncthreads(); }
  if (blk < 256) {
    const int o = blk;
    for (int it = t; it < 288; it += 256) {   // (tap, ci-octet)
      int tap = it >> 5, ci8 = it & 31;
      u64 pack = 0;
#pragma unroll
      for (int k = 0; k < 8; ++k)
        pack |= ((u64)f2sign8(wrow[(ci8 * 8 + k) * 9 + tap])) << (8 * k);
      int c64 = ci8 >> 3, kh = (ci8 >> 2) & 1, slot = ci8 & 3;
      *(u64*)(w1T + (size_t)((tap * 4 + c64) * 2 + kh) * 8192 + o * 32 + slot * 8) = pack;
    }
    if (t == 0) {
      float scale = red[0] / 2304.f;
      float inv = g1[o] / sqrtf(v1[o] + 1e-5f);
      ab[o]       = scale * inv;
      ab[256 + o] = be1[o] - m1[o] * inv;
    }
  } else {
    const int o = blk - 256;
    if (t < 32) {
      u64 pack = 0;
#pragma unroll
      for (int k = 0; k < 8; ++k)
        pack |= ((u64)f2sign8(wrow[t * 8 + k])) << (8 * k);
      int c64 = t >> 3, kh = (t >> 2) & 1, slot = t & 3;
      *(u64*)(w2T + (size_t)(c64 * 2 + kh) * 8192 + o * 32 + slot * 8) = pack;
    }
    if (t == 0) {
      float scale = red[0] / 256.f;
      float inv = g2[o] / sqrtf(v2[o] + 1e-5f);
      ab[512 + o] = scale * inv;
      ab[768 + o] = be2[o] - m2[o] * inv;
    }
  }
  if (blk == 0 && t == 0) lossdst[0] = lossin[0];
}

// ---------------- fused: act1-window + conv3x3 + conv1x1 ----------------
__global__ __launch_bounds__(512, 1) void fused_kernel(
    const float* __restrict__ x, const float* __restrict__ b11,
    const u8* __restrict__ w1T, const u8* __restrict__ w2T,
    const float* __restrict__ ab,
    const float* __restrict__ b12, const float* __restrict__ a1,
    const float* __restrict__ b13, const float* __restrict__ b21,
    const float* __restrict__ b22, const float* __restrict__ a2,
    const float* __restrict__ b23,
    float* __restrict__ dout)
{
  __shared__ __align__(16) u8 win[51200];   // 180px window (+pad-lane slack); reused for act2
  __shared__ float bsh[256];

  const int t = threadIdx.x;
  const int w = t >> 6;
  const int l = t & 63;
  const int l31 = l & 31;
  const int h32 = l >> 5;              // k-half selector
  const int mg = w & 1;                // m-pair group
  const int ng = w >> 1;               // och quad (64 och)
  const int pxblk = blockIdx.x;        // 224
  const int img = pxblk / 7;
  const int rowgrp = pxblk % 7;

  // per-lane epilogue params for nf = 0,1
  float al1[2], bt1[2], pA1[2], pS1[2], pB1[2], p21[2];
  float al2[2], bt2[2], pA2[2], pS2[2], pB2[2];
  int Ov[2];
#pragma unroll
  for (int nf = 0; nf < 2; ++nf) {
    int O = ng * 64 + nf * 32 + l31;
    Ov[nf] = O;
    al1[nf] = ab[O];       bt1[nf] = ab[256 + O];
    al2[nf] = ab[512 + O]; bt2[nf] = ab[768 + O];
    pA1[nf] = b12[O]; pS1[nf] = a1[O]; pB1[nf] = b13[O]; p21[nf] = b21[O];
    pA2[nf] = b22[O]; pS2[nf] = a2[O]; pB2[nf] = b23[O];
  }

  int basepix[2];
#pragma unroll
  for (int mi = 0; mi < 2; ++mi) {
    int pm = (mg * 2 + mi) * 32 + l31;
    int r = (pm * 293) >> 13;          // pm/28
    basepix[mi] = r * 30 + (pm - 28 * r);
  }

  char* wl = (char*)win;

  v16f acc[2][2];
  v16f zero16 = {0.f,0.f,0.f,0.f,0.f,0.f,0.f,0.f,0.f,0.f,0.f,0.f,0.f,0.f,0.f,0.f};
  f32x4 zero4 = {0.f, 0.f, 0.f, 0.f};
#pragma unroll
  for (int mi = 0; mi < 2; ++mi)
#pragma unroll
    for (int nf = 0; nf < 2; ++nf) acc[mi][nf] = zero16;

  // ---- prologue A: zero window (this IS the conv padding), stage b11 ----
  if (t < 256) bsh[t] = b11[t];
#pragma unroll
  for (int i = 0; i < 7; ++i) {
    int c = i * 512 + t;
    if (c < 3200) *(f32x4*)(wl + c * 16) = zero4;
  }
  __syncthreads();

  // ---- prologue B: act1 window from x (NCHW f32 -> sign fp8, XOR-swizzled) ----
  // window rows wr=0..5 <-> image rows rowgrp*4-1+wr; cols 1..28 <-> px 0..27.
#pragma unroll 1
  for (int wr = 0; wr < 6; ++wr) {
    int r_img = rowgrp * 4 - 1 + wr;
    if ((unsigned)r_img < 28u) {
#pragma unroll
      for (int it = 0; it < 4; ++it) {
        int u = it * 512 + t;          // 1792 units: ci(256) x px4(7)
        if (u < 1792) {
          int ci = u / 7;
          int p4 = u - ci * 7;
          float4 v = *(const float4*)(x + ((size_t)(img * 256 + ci)) * 784 + r_img * 28 + p4 * 4);
          float bb = bsh[ci];
          float vv[4] = {v.x, v.y, v.z, v.w};
          int pbase = wr * 30 + 1 + p4 * 4;
#pragma unroll
          for (int k = 0; k < 4; ++k) {
            int wp = pbase + k;
            wl[wp * 256 + (ci ^ ((wp & 15) << 4))] = f2sign8(vv[k] + bb);
          }
        }
      }
    }
  }
  __syncthreads();

  // ---- loaders / compute ----
  auto LOADB3 = [&](long2v (*dst)[2], int s) {   // 2 n-frags x 32B/lane
    int sc = (s < 36) ? s : 0;
    const char* base = (const char*)w1T + (size_t)sc * 16384 + h32 * 8192;
#pragma unroll
    for (int nf = 0; nf < 2; ++nf) {
      const char* p = base + (ng * 64 + nf * 32 + l31) * 32;
      dst[nf][0] = *(const long2v*)(p);
      dst[nf][1] = *(const long2v*)(p + 16);
    }
  };
  auto DSA3 = [&](long2v (*dst)[2], int s) {     // 2 m-frags x 32B/lane
    int sc = (s < 36) ? s : 0;
    int tap = sc >> 2;
    int c64 = sc & 3;
    int ti = (tap * 11) >> 5;                    // tap/3
    int tapoff = ti * 30 + (tap - 3 * ti);
    int off = c64 * 64 + h32 * 32;
#pragma unroll
    for (int mi = 0; mi < 2; ++mi) {
      int wp = basepix[mi] + tapoff;
      int sw = (wp & 15) << 4;
      const char* p = wl + wp * 256;
      dst[mi][0] = *(const long2v*)(p + ((off)      ^ sw));
      dst[mi][1] = *(const long2v*)(p + ((off + 16) ^ sw));
    }
  };
  auto COMP = [&](long2v (*a)[2], long2v (*bv)[2]) {   // 4 MFMA
    __builtin_amdgcn_s_setprio(1);
#pragma unroll
    for (int mi = 0; mi < 2; ++mi) {
      v8i a8 = mkv8(a[mi][0], a[mi][1]);
#pragma unroll
      for (int nf = 0; nf < 2; ++nf)
        acc[mi][nf] = __builtin_amdgcn_mfma_scale_f32_32x32x64_f8f6f4(
            a8, mkv8(bv[nf][0], bv[nf][1]), acc[mi][nf],
            0, 0, 0, 0x7F7F7F7Fu, 0, 0x7F7F7F7Fu);
    }
    __builtin_amdgcn_s_setprio(0);
  };

  // ---- conv3x3: 36 phases, A dbuf + B 3-set rotation, no barriers ----
  long2v A0[2][2], A1[2][2];
  long2v b0[2][2], b1[2][2], b2[2][2];
  DSA3(A0, 0); LOADB3(b0, 0); LOADB3(b1, 1);
#pragma unroll 1
  for (int i = 0; i < 6; ++i) {
    int p = i * 6;
    LOADB3(b2, p + 2); DSA3(A1, p + 1); COMP(A0, b0);
    LOADB3(b0, p + 3); DSA3(A0, p + 2); COMP(A1, b1);
    LOADB3(b1, p + 4); DSA3(A1, p + 3); COMP(A0, b2);
    LOADB3(b2, p + 5); DSA3(A0, p + 4); COMP(A1, b0);
    LOADB3(b0, p + 6); DSA3(A1, p + 5); COMP(A0, b1);
    LOADB3(b1, p + 7); DSA3(A0, p + 6); COMP(A1, b2);
  }
  __syncthreads();   // all window reads retired -> reuse win for act2

  // ---- epilogue 1: out1 = BN(conv)+x(f32 direct) -> bias/PReLU/bias; act2 -> LDS ----
  u32 pk[2][2][4][2];
#pragma unroll
  for (int mi = 0; mi < 2; ++mi) {
    int m = mg * 2 + mi;
#pragma unroll
    for (int rp = 0; rp < 4; ++rp) {
      int pixbase = m * 32 + 8 * rp + 4 * h32;
      bool valid = (m < 3) || (rp < 2);
#pragma unroll
      for (int nf = 0; nf < 2; ++nf) {
        int O = Ov[nf];
        float xv[4] = {0.f, 0.f, 0.f, 0.f};
        if (valid) {
          int hwm = rowgrp * 112 + pixbase;
          float4 xr = *(const float4*)(x + ((size_t)(img * 256 + O) * 784 + hwm));
          xv[0] = xr.x; xv[1] = xr.y; xv[2] = xr.z; xv[3] = xr.w;
        }
        float o1v[4];
#pragma unroll
        for (int reg = 0; reg < 4; ++reg) {
          int pix = pixbase + reg;
          float v = acc[mi][nf][rp * 4 + reg] * al1[nf] + bt1[nf] + xv[reg];
          float t1 = v + pA1[nf];
          t1 = (t1 > 0.f) ? t1 : pS1[nf] * t1;
          o1v[reg] = t1 + pB1[nf];
          wl[pix * 256 + (O ^ ((pix & 15) << 4))] = f2sign8(o1v[reg] + p21[nf]);
        }
        pk[mi][nf][rp][0] = (u32)f2b(o1v[0]) | ((u32)f2b(o1v[1]) << 16);
        pk[mi][nf][rp][1] = (u32)f2b(o1v[2]) | ((u32)f2b(o1v[3]) << 16);
      }
    }
  }
#pragma unroll
  for (int mi = 0; mi < 2; ++mi)
#pragma unroll
    for (int nf = 0; nf < 2; ++nf) acc[mi][nf] = zero16;

  asm volatile("s_waitcnt lgkmcnt(0)" ::: "memory");   // act2 LDS stores complete
  __builtin_amdgcn_s_barrier();

  // ---- conv1x1: 4 phases (K=256), A dbuf + B 2-set rotation ----
  auto LOADB1 = [&](long2v (*dst)[2], int sp) {
    const char* base = (const char*)w2T + (size_t)sp * 16384 + h32 * 8192;
#pragma unroll
    for (int nf = 0; nf < 2; ++nf) {
      const char* p = base + (ng * 64 + nf * 32 + l31) * 32;
      dst[nf][0] = *(const long2v*)(p);
      dst[nf][1] = *(const long2v*)(p + 16);
    }
  };
  auto DSA1 = [&](long2v (*dst)[2], int sp) {
    int off = sp * 64 + h32 * 32;
#pragma unroll
    for (int mi = 0; mi < 2; ++mi) {
      int pm = (mg * 2 + mi) * 32 + l31;
      int sw = (pm & 15) << 4;
      const char* p = wl + pm * 256;
      dst[mi][0] = *(const long2v*)(p + ((off)      ^ sw));
      dst[mi][1] = *(const long2v*)(p + ((off + 16) ^ sw));
    }
  };
  DSA1(A0, 0); LOADB1(b0, 0);
  DSA1(A1, 1); LOADB1(b1, 1); COMP(A0, b0);
  DSA1(A0, 2); LOADB1(b0, 2); COMP(A1, b1);
  DSA1(A1, 3); LOADB1(b1, 3); COMP(A0, b0);
  COMP(A1, b1);

  // ---- epilogue 2: out2 -> dout NCHW f32 ----
#pragma unroll
  for (int mi = 0; mi < 2; ++mi) {
    int m = mg * 2 + mi;
#pragma unroll
    for (int rp = 0; rp < 4; ++rp) {
      bool valid = (m < 3) || (rp < 2);
      if (!valid) continue;
      int pixbase = m * 32 + 8 * rp + 4 * h32;
      int hwm = rowgrp * 112 + pixbase;
#pragma unroll
      for (int nf = 0; nf < 2; ++nf) {
        int O = Ov[nf];
        float res[4];
        res[0] = b2f((u16)(pk[mi][nf][rp][0] & 0xFFFF));
        res[1] = b2f((u16)(pk[mi][nf][rp][0] >> 16));
        res[2] = b2f((u16)(pk[mi][nf][rp][1] & 0xFFFF));
        res[3] = b2f((u16)(pk[mi][nf][rp][1] >> 16));
        float r4v[4];
#pragma unroll
        for (int reg = 0; reg < 4; ++reg) {
          float v = acc[mi][nf][rp * 4 + reg] * al2[nf] + bt2[nf] + res[reg];
          float t1 = v + pA2[nf];
          t1 = (t1 > 0.f) ? t1 : pS2[nf] * t1;
          r4v[reg] = t1 + pB2[nf];
        }
        float4 r4 = {r4v[0], r4v[1], r4v[2], r4v[3]};
        *(float4*)(dout + ((size_t)(img * 256 + O)) * 784 + hwm) = r4;
      }
    }
  }
}

// ---------------- launcher ----------------
extern "C" void kernel_launch(void* const* d_in, const int* in_sizes, int n_in,
                              void* d_out, int out_size, void* d_ws, size_t ws_size,
                              hipStream_t stream) {
  const float* x    = (const float*)d_in[0];
  const float* loss = (const float*)d_in[1];
  const float* b11  = (const float*)d_in[2];
  const float* b12  = (const float*)d_in[3];
  const float* b13  = (const float*)d_in[4];
  const float* b21  = (const float*)d_in[5];
  const float* b22  = (const float*)d_in[6];
  const float* b23  = (const float*)d_in[7];
  const float* w1   = (const float*)d_in[8];
  const float* w2   = (const float*)d_in[9];
  const float* g1   = (const float*)d_in[10];
  const float* be1  = (const float*)d_in[11];
  const float* m1   = (const float*)d_in[12];
  const float* v1   = (const float*)d_in[13];
  const float* g2   = (const float*)d_in[14];
  const float* be2  = (const float*)d_in[15];
  const float* m2   = (const float*)d_in[16];
  const float* v2   = (const float*)d_in[17];
  const float* a1   = (const float*)d_in[18];
  const float* a2   = (const float*)d_in[19];

  char* ws = (char*)d_ws;
  u8*    w1T = (u8*)(ws + 0ull);           // 36 x 16KB = 589,824
  u8*    w2T = (u8*)(ws + 589824ull);      // 4 x 16KB = 65,536
  float* ab  = (float*)(ws + 655360ull);   // 4 x 256 f32

  float* out = (float*)d_out;

  prep_kernel<<<512, 256, 0, stream>>>(w1, w2, g1, be1, m1, v1, g2, be2, m2, v2,
                                       w1T, w2T, ab, out + (out_size - 1), loss);
  fused_kernel<<<224, 512, 0, stream>>>(x, b11, w1T, w2T, ab,
                                        b12, a1, b13, b21, b22, a2, b23, out);
}

// Round 16
// 40.042 us; speedup vs baseline: 1.2165x; 1.0900x over previous
//
#include <hip/hip_runtime.h>
#include <hip/hip_bf16.h>

// BasicBlock (ReActNet) fused pipeline, MI355X gfx950.  R16 = R15 switched to
// MX-scaled FP4 (mfma_scale_f32_32x32x64_f8f6f4, cbsz=blgp=4, scales=1.0).
// Signs {-1,0,+1} are exact in fp4 e2m1 (0xA/0x0/0x2); all staged bytes halve:
// window LDS 45->23KB, A=1 b128/frag, B=16B/lane, MFMA at 2x fp8 rate.
// act2 fp4 nibble pairing via __shfl_xor(,1); even lane writes the byte.

typedef unsigned short u16;
typedef unsigned char  u8;
typedef unsigned int   u32;
typedef unsigned long long u64;
typedef float f32x4 __attribute__((ext_vector_type(4)));
typedef long  long2v __attribute__((ext_vector_type(2)));
typedef int   v8i  __attribute__((ext_vector_type(8)));
typedef float v16f __attribute__((ext_vector_type(16)));

__device__ __forceinline__ float b2f(u16 u) {
  union { unsigned int i; float f; } c; c.i = ((unsigned int)u) << 16; return c.f;
}
__device__ __forceinline__ u16 f2b(float f) {
  unsigned int u = __builtin_bit_cast(unsigned int, f);
  unsigned int r = (u + 0x7FFFu + ((u >> 16) & 1u)) >> 16;   // RNE
  return (u16)r;
}
__device__ __forceinline__ u32 f2sign4(float v) {  // fp4 e2m1 of sign(v)
  return (v > 0.f) ? 0x2u : ((v < 0.f) ? 0xAu : 0x0u);
}
__device__ __forceinline__ v8i mkv8(long2v a, long2v b) {
  union { long2v l[2]; v8i v; } u; u.l[0] = a; u.l[1] = b; return u.v;
}

// ---- prep: fp4 sign weights (nibble-packed, k-ascending), BN fold, loss ----
// w1T: [(tap*4+c64)*2+kh][och 256][16B]; frag byte j = ci pair (base+2j, base+2j+1),
// low nibble = even ci.  w2T: [(c64*2+kh)][och 256][16B].
__global__ __launch_bounds__(256) void prep_kernel(
    const float* __restrict__ w1, const float* __restrict__ w2,
    const float* __restrict__ g1, const float* __restrict__ be1,
    const float* __restrict__ m1, const float* __restrict__ v1,
    const float* __restrict__ g2, const float* __restrict__ be2,
    const float* __restrict__ m2, const float* __restrict__ v2,
    u8* __restrict__ w1T, u8* __restrict__ w2T,
    float* __restrict__ ab,
    float* __restrict__ lossdst, const float* __restrict__ lossin)
{
  __shared__ float wrow[2304];
  __shared__ float red[256];
  const int t = threadIdx.x;
  const int blk = blockIdx.x;
  float s = 0.f;
  if (blk < 256) {                       // w1 row o: stage coalesced, then pack
    const int o = blk;
    const float4* src = (const float4*)(w1 + o * 2304);
#pragma unroll
    for (int i = 0; i < 3; ++i) {
      int c = i * 256 + t;
      if (c < 576) {
        float4 v = src[c];
        wrow[c * 4 + 0] = v.x; wrow[c * 4 + 1] = v.y;
        wrow[c * 4 + 2] = v.z; wrow[c * 4 + 3] = v.w;
        s += fabsf(v.x) + fabsf(v.y) + fabsf(v.z) + fabsf(v.w);
      }
    }
  } else {
    const int o = blk - 256;
    float v = w2[o * 256 + t];
    wrow[t] = v;
    s = fabsf(v);
  }
  red[t] = s;
  __syncthreads();
  for (int st = 128; st > 0; st >>= 1) { if (t < st) red[t] += red[t + st]; __syncthreads(); }
  if (blk < 256) {
    const int o = blk;
    for (int it = t; it < 288; it += 256) {   // (tap, ci-octet)
      int tap = it >> 5, ci8 = it & 31;
      u32 pack = 0;
#pragma unroll
      for (int k = 0; k < 8; ++k)
        pack |= f2sign4(wrow[(ci8 * 8 + k) * 9 + tap]) << (4 * k);
      int c64 = ci8 >> 3, kh = (ci8 >> 2) & 1, slot = ci8 & 3;
      *(u32*)(w1T + (size_t)((tap * 4 + c64) * 2 + kh) * 4096 + o * 16 + slot * 4) = pack;
    }
    if (t == 0) {
      float scale = red[0] / 2304.f;
      float inv = g1[o] / sqrtf(v1[o] + 1e-5f);
      ab[o]       = scale * inv;
      ab[256 + o] = be1[o] - m1[o] * inv;
    }
  } else {
    const int o = blk - 256;
    if (t < 32) {
      u32 pack = 0;
#pragma unroll
      for (int k = 0; k < 8; ++k)
        pack |= f2sign4(wrow[t * 8 + k]) << (4 * k);
      int c64 = t >> 3, kh = (t >> 2) & 1, slot = t & 3;
      *(u32*)(w2T + (size_t)(c64 * 2 + kh) * 4096 + o * 16 + slot * 4) = pack;
    }
    if (t == 0) {
      float scale = red[0] / 256.f;
      float inv = g2[o] / sqrtf(v2[o] + 1e-5f);
      ab[512 + o] = scale * inv;
      ab[768 + o] = be2[o] - m2[o] * inv;
    }
  }
  if (blk == 0 && t == 0) lossdst[0] = lossin[0];
}

// ---------------- fused: act1-window(fp4) + conv3x3 + conv1x1 ----------------
__global__ __launch_bounds__(512, 1) void fused_kernel(
    const float* __restrict__ x, const float* __restrict__ b11,
    const u8* __restrict__ w1T, const u8* __restrict__ w2T,
    const float* __restrict__ ab,
    const float* __restrict__ b12, const float* __restrict__ a1,
    const float* __restrict__ b13, const float* __restrict__ b21,
    const float* __restrict__ b22, const float* __restrict__ a2,
    const float* __restrict__ b23,
    float* __restrict__ dout)
{
  __shared__ __align__(16) u8 win[26112];   // 204 rows x 128B fp4 (180 window + OOB slack)
  __shared__ float bsh[256];

  const int t = threadIdx.x;
  const int w = t >> 6;
  const int l = t & 63;
  const int l31 = l & 31;
  const int h32 = l >> 5;              // k-half selector
  const int mg = w & 1;                // m-pair group
  const int ng = w >> 1;               // och quad (64 och)
  const int pxblk = blockIdx.x;        // 224
  const int img = pxblk / 7;
  const int rowgrp = pxblk % 7;

  // per-lane epilogue params for nf = 0,1
  float al1[2], bt1[2], pA1[2], pS1[2], pB1[2], p21[2];
  float al2[2], bt2[2], pA2[2], pS2[2], pB2[2];
  int Ov[2];
#pragma unroll
  for (int nf = 0; nf < 2; ++nf) {
    int O = ng * 64 + nf * 32 + l31;
    Ov[nf] = O;
    al1[nf] = ab[O];       bt1[nf] = ab[256 + O];
    al2[nf] = ab[512 + O]; bt2[nf] = ab[768 + O];
    pA1[nf] = b12[O]; pS1[nf] = a1[O]; pB1[nf] = b13[O]; p21[nf] = b21[O];
    pA2[nf] = b22[O]; pS2[nf] = a2[O]; pB2[nf] = b23[O];
  }

  int basepix[2];
#pragma unroll
  for (int mi = 0; mi < 2; ++mi) {
    int pm = (mg * 2 + mi) * 32 + l31;
    int r = (pm * 293) >> 13;          // pm/28
    basepix[mi] = r * 30 + (pm - 28 * r);
  }

  char* wl = (char*)win;

  v16f acc[2][2];
  v16f zero16 = {0.f,0.f,0.f,0.f,0.f,0.f,0.f,0.f,0.f,0.f,0.f,0.f,0.f,0.f,0.f,0.f};
  f32x4 zero4 = {0.f, 0.f, 0.f, 0.f};
  long2v zl2 = {0, 0};
#pragma unroll
  for (int mi = 0; mi < 2; ++mi)
#pragma unroll
    for (int nf = 0; nf < 2; ++nf) acc[mi][nf] = zero16;

  // ---- prologue A: zero window (this IS the conv padding), stage b11 ----
  if (t < 256) bsh[t] = b11[t];
#pragma unroll
  for (int i = 0; i < 4; ++i) {
    int c = i * 512 + t;
    if (c < 1632) *(f32x4*)(wl + c * 16) = zero4;
  }
  __syncthreads();

  // ---- prologue B: act1 window from x -> fp4 nibbles (2 ci/byte), XOR-swizzled ----
  // window rows wr=0..5 <-> image rows rowgrp*4-1+wr; cols 1..28 <-> px 0..27.
#pragma unroll 1
  for (int wr = 0; wr < 6; ++wr) {
    int r_img = rowgrp * 4 - 1 + wr;
    if ((unsigned)r_img < 28u) {
#pragma unroll
      for (int it = 0; it < 2; ++it) {
        int u = it * 512 + t;          // 896 units: ci-pair(128) x px4(7)
        if (u < 896) {
          int c2 = (u * 9363) >> 16;   // u/7
          int p4 = u - c2 * 7;
          const float* xb = x + ((size_t)(img * 256 + 2 * c2)) * 784 + r_img * 28 + p4 * 4;
          float4 v0 = *(const float4*)(xb);
          float4 v1 = *(const float4*)(xb + 784);
          float b0v = bsh[2 * c2], b1v = bsh[2 * c2 + 1];
          float lo[4] = {v0.x, v0.y, v0.z, v0.w};
          float hi[4] = {v1.x, v1.y, v1.z, v1.w};
          int pbase = wr * 30 + 1 + p4 * 4;
#pragma unroll
          for (int k = 0; k < 4; ++k) {
            int wp = pbase + k;
            u8 byte = (u8)(f2sign4(lo[k] + b0v) | (f2sign4(hi[k] + b1v) << 4));
            wl[wp * 128 + ((((c2 >> 4) ^ (wp & 7)) << 4) | (c2 & 15))] = byte;
          }
        }
      }
    }
  }
  __syncthreads();

  // ---- loaders / compute (fp4) ----
  auto LOADB3 = [&](long2v* dst, int s) {        // 2 n-frags x 16B/lane
    int sc = (s < 36) ? s : 0;
    const char* base = (const char*)w1T + (size_t)sc * 8192 + h32 * 4096;
#pragma unroll
    for (int nf = 0; nf < 2; ++nf)
      dst[nf] = *(const long2v*)(base + (ng * 64 + nf * 32 + l31) * 16);
  };
  auto DSA3 = [&](long2v* dst, int s) {          // 2 m-frags x 16B/lane
    int sc = (s < 36) ? s : 0;
    int tap = sc >> 2;
    int c64 = sc & 3;
    int ti = (tap * 11) >> 5;                    // tap/3
    int tapoff = ti * 30 + (tap - 3 * ti);
    int slot = c64 * 2 + h32;
#pragma unroll
    for (int mi = 0; mi < 2; ++mi) {
      int wp = basepix[mi] + tapoff;
      dst[mi] = *(const long2v*)(wl + wp * 128 + ((slot ^ (wp & 7)) << 4));
    }
  };
  auto COMP = [&](long2v* a, long2v* bv) {       // 4 MFMA, fp4 fmt
    __builtin_amdgcn_s_setprio(1);
#pragma unroll
    for (int mi = 0; mi < 2; ++mi) {
      v8i a8 = mkv8(a[mi], zl2);
#pragma unroll
      for (int nf = 0; nf < 2; ++nf)
        acc[mi][nf] = __builtin_amdgcn_mfma_scale_f32_32x32x64_f8f6f4(
            a8, mkv8(bv[nf], zl2), acc[mi][nf],
            4, 4,                        // cbsz = blgp = fp4 e2m1
            0, 0x7F7F7F7Fu, 0, 0x7F7F7F7Fu);
    }
    __builtin_amdgcn_s_setprio(0);
  };

  // ---- conv3x3: 36 phases, A dbuf + B 3-set rotation, no barriers ----
  long2v A0[2], A1[2];
  long2v b0[2], b1[2], b2[2];
  DSA3(A0, 0); LOADB3(b0, 0); LOADB3(b1, 1);
#pragma unroll 1
  for (int i = 0; i < 6; ++i) {
    int p = i * 6;
    LOADB3(b2, p + 2); DSA3(A1, p + 1); COMP(A0, b0);
    LOADB3(b0, p + 3); DSA3(A0, p + 2); COMP(A1, b1);
    LOADB3(b1, p + 4); DSA3(A1, p + 3); COMP(A0, b2);
    LOADB3(b2, p + 5); DSA3(A0, p + 4); COMP(A1, b0);
    LOADB3(b0, p + 6); DSA3(A1, p + 5); COMP(A0, b1);
    LOADB3(b1, p + 7); DSA3(A0, p + 6); COMP(A1, b2);
  }
  __syncthreads();   // all window reads retired -> reuse win for act2 (fp4)

  // ---- epilogue 1: out1 = BN(conv)+x(f32) -> bias/PReLU/bias; act2 fp4 -> LDS ----
  u32 pk[2][2][4][2];
#pragma unroll
  for (int mi = 0; mi < 2; ++mi) {
    int m = mg * 2 + mi;
#pragma unroll
    for (int rp = 0; rp < 4; ++rp) {
      int pixbase = m * 32 + 8 * rp + 4 * h32;
      bool valid = (m < 3) || (rp < 2);
#pragma unroll
      for (int nf = 0; nf < 2; ++nf) {
        int O = Ov[nf];
        float xv[4] = {0.f, 0.f, 0.f, 0.f};
        if (valid) {
          int hwm = rowgrp * 112 + pixbase;
          float4 xr = *(const float4*)(x + ((size_t)(img * 256 + O) * 784 + hwm));
          xv[0] = xr.x; xv[1] = xr.y; xv[2] = xr.z; xv[3] = xr.w;
        }
        float o1v[4];
        u32 mynibs = 0;
#pragma unroll
        for (int reg = 0; reg < 4; ++reg) {
          float v = acc[mi][nf][rp * 4 + reg] * al1[nf] + bt1[nf] + xv[reg];
          float t1 = v + pA1[nf];
          t1 = (t1 > 0.f) ? t1 : pS1[nf] * t1;
          o1v[reg] = t1 + pB1[nf];
          mynibs |= f2sign4(o1v[reg] + p21[nf]) << (4 * reg);
        }
        u32 partner = __shfl_xor((int)mynibs, 1);
        if ((l31 & 1) == 0) {          // even och lane writes the shared byte
          int c2 = O >> 1;
#pragma unroll
          for (int reg = 0; reg < 4; ++reg) {
            int pix = pixbase + reg;
            u8 byte = (u8)(((mynibs >> (4 * reg)) & 0xF) |
                           (((partner >> (4 * reg)) & 0xF) << 4));
            wl[pix * 128 + ((((c2 >> 4) ^ (pix & 7)) << 4) | (c2 & 15))] = byte;
          }
        }
        pk[mi][nf][rp][0] = (u32)f2b(o1v[0]) | ((u32)f2b(o1v[1]) << 16);
        pk[mi][nf][rp][1] = (u32)f2b(o1v[2]) | ((u32)f2b(o1v[3]) << 16);
      }
    }
  }
#pragma unroll
  for (int mi = 0; mi < 2; ++mi)
#pragma unroll
    for (int nf = 0; nf < 2; ++nf) acc[mi][nf] = zero16;

  asm volatile("s_waitcnt lgkmcnt(0)" ::: "memory");   // act2 LDS stores complete
  __builtin_amdgcn_s_barrier();

  // ---- conv1x1: 4 phases (K=256), A dbuf + B 2-set rotation ----
  auto LOADB1 = [&](long2v* dst, int sp) {
    const char* base = (const char*)w2T + (size_t)sp * 8192 + h32 * 4096;
#pragma unroll
    for (int nf = 0; nf < 2; ++nf)
      dst[nf] = *(const long2v*)(base + (ng * 64 + nf * 32 + l31) * 16);
  };
  auto DSA1 = [&](long2v* dst, int sp) {
    int slot = sp * 2 + h32;
#pragma unroll
    for (int mi = 0; mi < 2; ++mi) {
      int pm = (mg * 2 + mi) * 32 + l31;
      dst[mi] = *(const long2v*)(wl + pm * 128 + ((slot ^ (pm & 7)) << 4));
    }
  };
  DSA1(A0, 0); LOADB1(b0, 0);
  DSA1(A1, 1); LOADB1(b1, 1); COMP(A0, b0);
  DSA1(A0, 2); LOADB1(b0, 2); COMP(A1, b1);
  DSA1(A1, 3); LOADB1(b1, 3); COMP(A0, b0);
  COMP(A1, b1);

  // ---- epilogue 2: out2 -> dout NCHW f32 ----
#pragma unroll
  for (int mi = 0; mi < 2; ++mi) {
    int m = mg * 2 + mi;
#pragma unroll
    for (int rp = 0; rp < 4; ++rp) {
      bool valid = (m < 3) || (rp < 2);
      if (!valid) continue;
      int pixbase = m * 32 + 8 * rp + 4 * h32;
      int hwm = rowgrp * 112 + pixbase;
#pragma unroll
      for (int nf = 0; nf < 2; ++nf) {
        int O = Ov[nf];
        float res[4];
        res[0] = b2f((u16)(pk[mi][nf][rp][0] & 0xFFFF));
        res[1] = b2f((u16)(pk[mi][nf][rp][0] >> 16));
        res[2] = b2f((u16)(pk[mi][nf][rp][1] & 0xFFFF));
        res[3] = b2f((u16)(pk[mi][nf][rp][1] >> 16));
        float r4v[4];
#pragma unroll
        for (int reg = 0; reg < 4; ++reg) {
          float v = acc[mi][nf][rp * 4 + reg] * al2[nf] + bt2[nf] + res[reg];
          float t1 = v + pA2[nf];
          t1 = (t1 > 0.f) ? t1 : pS2[nf] * t1;
          r4v[reg] = t1 + pB2[nf];
        }
        float4 r4 = {r4v[0], r4v[1], r4v[2], r4v[3]};
        *(float4*)(dout + ((size_t)(img * 256 + O)) * 784 + hwm) = r4;
      }
    }
  }
}

// ---------------- launcher ----------------
extern "C" void kernel_launch(void* const* d_in, const int* in_sizes, int n_in,
                              void* d_out, int out_size, void* d_ws, size_t ws_size,
                              hipStream_t stream) {
  const float* x    = (const float*)d_in[0];
  const float* loss = (const float*)d_in[1];
  const float* b11  = (const float*)d_in[2];
  const float* b12  = (const float*)d_in[3];
  const float* b13  = (const float*)d_in[4];
  const float* b21  = (const float*)d_in[5];
  const float* b22  = (const float*)d_in[6];
  const float* b23  = (const float*)d_in[7];
  const float* w1   = (const float*)d_in[8];
  const float* w2   = (const float*)d_in[9];
  const float* g1   = (const float*)d_in[10];
  const float* be1  = (const float*)d_in[11];
  const float* m1   = (const float*)d_in[12];
  const float* v1   = (const float*)d_in[13];
  const float* g2   = (const float*)d_in[14];
  const float* be2  = (const float*)d_in[15];
  const float* m2   = (const float*)d_in[16];
  const float* v2   = (const float*)d_in[17];
  const float* a1   = (const float*)d_in[18];
  const float* a2   = (const float*)d_in[19];

  char* ws = (char*)d_ws;
  u8*    w1T = (u8*)(ws + 0ull);           // 36 x 8KB = 294,912
  u8*    w2T = (u8*)(ws + 294912ull);      // 4 x 8KB = 32,768
  float* ab  = (float*)(ws + 327680ull);   // 4 x 256 f32

  float* out = (float*)d_out;

  prep_kernel<<<512, 256, 0, stream>>>(w1, w2, g1, be1, m1, v1, g2, be2, m2, v2,
                                       w1T, w2T, ab, out + (out_size - 1), loss);
  fused_kernel<<<224, 512, 0, stream>>>(x, b11, w1T, w2T, ab,
                                        b12, a1, b13, b21, b22, a2, b23, out);
}